// Round 1
// baseline (2961.454 us; speedup 1.0000x reference)
//
#include <hip/hip_runtime.h>

typedef __bf16 bf16x8 __attribute__((ext_vector_type(8)));
typedef float floatx4 __attribute__((ext_vector_type(4)));

__device__ __forceinline__ float u2f(unsigned short u) {
  union { unsigned int i; float f; } v; v.i = ((unsigned int)u) << 16; return v.f;
}
__device__ __forceinline__ unsigned short f2b(float f) {
  union { float f; unsigned int i; } v; v.f = f;
  unsigned int r = (v.i + 0x7fffu + ((v.i >> 16) & 1u)) >> 16;
  return (unsigned short)r;
}

// ---------------------------------------------------------------------------
// Generic GEMM: C[M,N] = A[M,K](bf16) @ W[N,K](fp32)^T + bias
// mode 0: store bf16; mode 1: relu, store bf16; mode 2: heads epilogue:
//   outF[(m*8+t)*N + n] = acc + bias[n] + t * W[n*ldw + K]   (fp32)
// Block tile 128x128, BK=32, 256 threads (4 waves, each 64x64).
// ---------------------------------------------------------------------------
#define LDS_STRIDE 48

__global__ __launch_bounds__(256) void gemm_kernel(
    const unsigned short* __restrict__ A, int lda,
    const float* __restrict__ W, int ldw,
    const float* __restrict__ bias,
    unsigned short* __restrict__ outB, float* __restrict__ outF,
    int M, int N, int K, int ldc, int mode)
{
  __shared__ unsigned short As[128 * LDS_STRIDE];
  __shared__ unsigned short Bs[128 * LDS_STRIDE];

  const int tid  = threadIdx.x;
  const int m0   = blockIdx.y * 128;
  const int n0   = blockIdx.x * 128;
  const int wave = tid >> 6;
  const int lane = tid & 63;
  const int wm   = (wave >> 1) * 64;
  const int wn   = (wave & 1) * 64;
  const int lr   = lane & 15;     // row-in-tile for frags / col for C
  const int lq   = lane >> 4;     // quad

  floatx4 acc[4][4];
#pragma unroll
  for (int i = 0; i < 4; i++)
#pragma unroll
    for (int j = 0; j < 4; j++)
      acc[i][j] = (floatx4){0.f, 0.f, 0.f, 0.f};

  for (int k0 = 0; k0 < K; k0 += 32) {
    __syncthreads();
    // stage A tile [128 x 32] bf16 : 2 x 16B per thread
#pragma unroll
    for (int i = 0; i < 2; i++) {
      int c   = tid + i * 256;
      int row = c >> 2;
      int k8  = (c & 3) * 8;
      uint4 val = {0u, 0u, 0u, 0u};
      if (m0 + row < M)
        val = *(const uint4*)(A + (size_t)(m0 + row) * lda + k0 + k8);
      *(uint4*)(&As[row * LDS_STRIDE + k8]) = val;
    }
    // stage W tile [128 x 32] fp32 -> bf16 : 4 x 4 floats per thread
#pragma unroll
    for (int i = 0; i < 4; i++) {
      int c   = tid + i * 256;
      int row = c >> 3;
      int k4  = (c & 7) * 4;
      float f0 = 0.f, f1 = 0.f, f2 = 0.f, f3 = 0.f;
      if (n0 + row < N) {
        const float* p = W + (size_t)(n0 + row) * ldw + k0 + k4;
        f0 = p[0]; f1 = p[1]; f2 = p[2]; f3 = p[3];
      }
      ushort4 pk;
      pk.x = f2b(f0); pk.y = f2b(f1); pk.z = f2b(f2); pk.w = f2b(f3);
      *(ushort4*)(&Bs[row * LDS_STRIDE + k4]) = pk;
    }
    __syncthreads();

    bf16x8 af[4], bfr[4];
#pragma unroll
    for (int t = 0; t < 4; t++) {
      af[t]  = *(const bf16x8*)(&As[(wm + t * 16 + lr) * LDS_STRIDE + lq * 8]);
      bfr[t] = *(const bf16x8*)(&Bs[(wn + t * 16 + lr) * LDS_STRIDE + lq * 8]);
    }
#pragma unroll
    for (int tm = 0; tm < 4; tm++)
#pragma unroll
      for (int tn = 0; tn < 4; tn++)
        acc[tm][tn] = __builtin_amdgcn_mfma_f32_16x16x32_bf16(
            af[tm], bfr[tn], acc[tm][tn], 0, 0, 0);
  }

  // epilogue
#pragma unroll
  for (int tm = 0; tm < 4; tm++) {
#pragma unroll
    for (int tn = 0; tn < 4; tn++) {
      int gcol = n0 + wn + tn * 16 + lr;
      if (gcol >= N) continue;
      float bs = bias[gcol];
      if (mode == 2) {
        float wl = W[(size_t)gcol * ldw + K];
#pragma unroll
        for (int r = 0; r < 4; r++) {
          int grow = m0 + wm + tm * 16 + lq * 4 + r;
          float base = acc[tm][tn][r] + bs;
          float* op = outF + ((size_t)grow * 8) * (size_t)N + gcol;
#pragma unroll
          for (int t = 0; t < 8; t++)
            op[(size_t)t * N] = base + (float)t * wl;
        }
      } else {
#pragma unroll
        for (int r = 0; r < 4; r++) {
          int grow = m0 + wm + tm * 16 + lq * 4 + r;
          if (grow < M) {
            float v = acc[tm][tn][r] + bs;
            if (mode == 1) v = fmaxf(v, 0.f);
            outB[(size_t)grow * ldc + gcol] = f2b(v);
          }
        }
      }
    }
  }
}

// ---------------------------------------------------------------------------
// Attention: one block per (b,h). S=200, hd=16, fp32 softmax in LDS.
// qkv: [25600, 384] bf16 rows (q|k|v), out: [25600, 128] bf16 (heads concat)
// ---------------------------------------------------------------------------
__global__ __launch_bounds__(256) void attn_kernel(
    const unsigned short* __restrict__ qkv, unsigned short* __restrict__ out)
{
  __shared__ float qsh[200 * 20];
  __shared__ float ksh[200 * 20];
  __shared__ float vsh[200 * 20];
  __shared__ float sc[16 * 201];

  const int bh = blockIdx.x;
  const int b = bh >> 3, h = bh & 7;
  const int tid = threadIdx.x;
  const size_t rowbase = (size_t)b * 200;

  for (int i = tid; i < 3200; i += 256) {
    int s = i >> 4, d = i & 15;
    const unsigned short* base = qkv + (rowbase + s) * 384 + h * 16 + d;
    qsh[s * 20 + d] = u2f(base[0]);
    ksh[s * 20 + d] = u2f(base[128]);
    vsh[s * 20 + d] = u2f(base[256]);
  }
  __syncthreads();

  const int qr = tid >> 4;   // 0..15 query row in tile
  const int kl = tid & 15;   // 0..15 lane within row

  for (int q0 = 0; q0 < 200; q0 += 16) {
    int rows = (200 - q0 < 16) ? (200 - q0) : 16;
    bool act = qr < rows;
    float4 qa, qb, qc, qd;
    if (act) {
      const float4* qp = (const float4*)&qsh[(q0 + qr) * 20];
      qa = qp[0]; qb = qp[1]; qc = qp[2]; qd = qp[3];
      for (int kk = kl; kk < 200; kk += 16) {
        const float4* kp = (const float4*)&ksh[kk * 20];
        float4 ka = kp[0], kb = kp[1], kc = kp[2], kd = kp[3];
        float dot = qa.x * ka.x + qa.y * ka.y + qa.z * ka.z + qa.w * ka.w
                  + qb.x * kb.x + qb.y * kb.y + qb.z * kb.z + qb.w * kb.w
                  + qc.x * kc.x + qc.y * kc.y + qc.z * kc.z + qc.w * kc.w
                  + qd.x * kd.x + qd.y * kd.y + qd.z * kd.z + qd.w * kd.w;
        sc[qr * 201 + kk] = dot * 0.25f;
      }
    }
    float mx = -1e30f, sum = 0.f;
    if (act)
      for (int kk = kl; kk < 200; kk += 16)
        mx = fmaxf(mx, sc[qr * 201 + kk]);
    mx = fmaxf(mx, __shfl_xor(mx, 1, 16));
    mx = fmaxf(mx, __shfl_xor(mx, 2, 16));
    mx = fmaxf(mx, __shfl_xor(mx, 4, 16));
    mx = fmaxf(mx, __shfl_xor(mx, 8, 16));
    if (act)
      for (int kk = kl; kk < 200; kk += 16) {
        float e = __expf(sc[qr * 201 + kk] - mx);
        sc[qr * 201 + kk] = e;
        sum += e;
      }
    sum += __shfl_xor(sum, 1, 16);
    sum += __shfl_xor(sum, 2, 16);
    sum += __shfl_xor(sum, 4, 16);
    sum += __shfl_xor(sum, 8, 16);
    float inv = 1.0f / sum;
    __syncthreads();
    if (act) {
      float a0 = 0.f;
      for (int kk = 0; kk < 200; kk++)
        a0 += sc[qr * 201 + kk] * vsh[kk * 20 + kl];
      out[(rowbase + q0 + qr) * 128 + h * 16 + kl] = f2b(a0 * inv);
    }
    __syncthreads();
  }
}

// ---------------------------------------------------------------------------
// Fused residual + LayerNorm (in place on x): x = LN(x + sub) * g + b
// one wave per row (128 elems, 2 per lane), 4 rows per block
// ---------------------------------------------------------------------------
__global__ __launch_bounds__(256) void ln_kernel(
    unsigned short* __restrict__ x, const unsigned short* __restrict__ sub,
    const float* __restrict__ g, const float* __restrict__ b)
{
  int row  = blockIdx.x * 4 + (threadIdx.x >> 6);
  int lane = threadIdx.x & 63;
  size_t base = (size_t)row * 128;
  int d0 = lane * 2, d1 = d0 + 1;
  float v0 = u2f(x[base + d0]) + u2f(sub[base + d0]);
  float v1 = u2f(x[base + d1]) + u2f(sub[base + d1]);
  float s  = v0 + v1;
  float ss = v0 * v0 + v1 * v1;
  for (int m = 1; m < 64; m <<= 1) {
    s  += __shfl_xor(s, m, 64);
    ss += __shfl_xor(ss, m, 64);
  }
  float mean = s * (1.f / 128.f);
  float var  = ss * (1.f / 128.f) - mean * mean;
  float r    = rsqrtf(var + 1e-5f);
  x[base + d0] = f2b((v0 - mean) * r * g[d0] + b[d0]);
  x[base + d1] = f2b((v1 - mean) * r * g[d1] + b[d1]);
}

// ---------------------------------------------------------------------------
__global__ __launch_bounds__(128) void gather_kernel(
    const int* __restrict__ ids, const float* __restrict__ table,
    unsigned short* __restrict__ x)
{
  int rid = blockIdx.x;
  int d   = threadIdx.x;
  int id  = ids[rid];
  x[(size_t)rid * 128 + d] = f2b(table[(size_t)id * 128 + d]);
}

__global__ __launch_bounds__(128) void pool_kernel(
    const unsigned short* __restrict__ x, unsigned short* __restrict__ hcat,
    int col0)
{
  int b = blockIdx.x;
  int d = threadIdx.x;
  float s = 0.f;
  for (int t = 0; t < 200; t++)
    s += u2f(x[(size_t)(b * 200 + t) * 128 + d]);
  hcat[b * 256 + col0 + d] = f2b(s * (1.f / 200.f));
}

// ---------------------------------------------------------------------------
static void gemm(hipStream_t st, const unsigned short* A, int lda,
                 const float* W, int ldw, const float* bias,
                 unsigned short* outB, float* outF,
                 int M, int N, int K, int ldc, int mode)
{
  dim3 grid((N + 127) / 128, (M + 127) / 128);
  gemm_kernel<<<grid, dim3(256), 0, st>>>(A, lda, W, ldw, bias, outB, outF,
                                          M, N, K, ldc, mode);
}

extern "C" void kernel_launch(void* const* d_in, const int* in_sizes, int n_in,
                              void* d_out, int out_size, void* d_ws, size_t ws_size,
                              hipStream_t stream)
{
  const int*   tab_ids     = (const int*)d_in[0];
  const int*   idx_ids     = (const int*)d_in[1];
  const float* table_embed = (const float*)d_in[2];
  const float* idx_embed   = (const float*)d_in[3];
  const float* Wqkv = (const float*)d_in[4];
  const float* bqkv = (const float*)d_in[5];
  const float* Wo   = (const float*)d_in[6];
  const float* bo   = (const float*)d_in[7];
  const float* ln1g = (const float*)d_in[8];
  const float* ln1b = (const float*)d_in[9];
  const float* W1   = (const float*)d_in[10];
  const float* b1   = (const float*)d_in[11];
  const float* W2   = (const float*)d_in[12];
  const float* b2   = (const float*)d_in[13];
  const float* ln2g = (const float*)d_in[14];
  const float* ln2b = (const float*)d_in[15];
  const float* Wlin = (const float*)d_in[16];
  const float* blin = (const float*)d_in[17];
  const float* Wtab = (const float*)d_in[18];
  const float* btab = (const float*)d_in[19];
  const float* Widx = (const float*)d_in[20];
  const float* bidx = (const float*)d_in[21];
  float* out = (float*)d_out;
  char*  ws  = (char*)d_ws;

  const size_t off_x    = 0;                 // 25600*128 bf16 = 6,553,600
  const size_t off_qkv  = 6553600;           // 25600*384 bf16 = 19,660,800 (o2 aliases)
  const size_t off_attn = 26214400;          // 25600*128 bf16
  const size_t off_mid  = 32768000;          // FFN intermediate (chunked)

  int nc = 16;
  if (off_mid + 104857600 / 1 + 196608 <= ws_size) nc = 1;
  else if (off_mid + 104857600 / 4 + 196608 <= ws_size) nc = 4;
  size_t midbytes = (size_t)104857600 / nc;
  const size_t off_hcat = off_mid + midbytes;
  const size_t off_h    = off_hcat + 65536;

  unsigned short* x    = (unsigned short*)(ws + off_x);
  unsigned short* qkv  = (unsigned short*)(ws + off_qkv);
  unsigned short* o2   = qkv;                       // reuse (qkv dead after attn)
  unsigned short* attn = (unsigned short*)(ws + off_attn);
  unsigned short* mid  = (unsigned short*)(ws + off_mid);
  unsigned short* hcat = (unsigned short*)(ws + off_hcat);
  unsigned short* h    = (unsigned short*)(ws + off_h);

  const int chunk = 25600 / nc;

  for (int e = 0; e < 2; e++) {
    gather_kernel<<<25600, 128, 0, stream>>>(
        e == 0 ? tab_ids : idx_ids,
        e == 0 ? table_embed : idx_embed, x);
    for (int l = 0; l < 2; l++) {
      int pi = e * 2 + l;
      gemm(stream, x, 128, Wqkv + (size_t)pi * 384 * 128, 128,
           bqkv + (size_t)pi * 384, qkv, nullptr, 25600, 384, 128, 384, 0);
      attn_kernel<<<1024, 256, 0, stream>>>(qkv, attn);
      gemm(stream, attn, 128, Wo + (size_t)pi * 128 * 128, 128,
           bo + (size_t)pi * 128, o2, nullptr, 25600, 128, 128, 128, 0);
      ln_kernel<<<6400, 256, 0, stream>>>(x, o2, ln1g + pi * 128, ln1b + pi * 128);
      for (int c = 0; c < nc; c++) {
        gemm(stream, x + (size_t)c * chunk * 128, 128,
             W1 + (size_t)pi * 2048 * 128, 128, b1 + (size_t)pi * 2048,
             mid, nullptr, chunk, 2048, 128, 2048, 1);
        gemm(stream, mid, 2048,
             W2 + (size_t)pi * 128 * 2048, 2048, b2 + (size_t)pi * 128,
             o2 + (size_t)c * chunk * 128, nullptr, chunk, 128, 2048, 128, 0);
      }
      ln_kernel<<<6400, 256, 0, stream>>>(x, o2, ln2g + pi * 128, ln2b + pi * 128);
    }
    pool_kernel<<<128, 128, 0, stream>>>(x, hcat, e * 128);
  }

  gemm(stream, hcat, 256, Wlin, 256, blin, h, nullptr, 128, 512, 256, 512, 1);
  gemm(stream, h, 512, Wtab, 513, btab, nullptr, out,           128, 1000,   512, 1000,   2);
  gemm(stream, h, 512, Widx, 513, bidx, nullptr, out + 1024000, 128, 100000, 512, 100000, 2);
}